// Round 6
// baseline (617.217 us; speedup 1.0000x reference)
//
#include <hip/hip_runtime.h>
#include <math.h>

#define BB 1024
#define NN 4096
#define HH 32
#define PP 4                  // K1 sub-blocks per batch (each handles NN/PP rows)
#define RK1 (NN / PP)         // 1024 rows per K1 block
#define CHUNK 128             // batches per pipeline chunk (64 MB of ne)
#define NCH (BB / CHUNK)      // 8 chunks
#define K1B (CHUNK * PP)      // 512 K1-role blocks per chunk
#define K3B CHUNK             // 128 K3-role blocks per chunk

// ws layout (floats): [BB*PP*HH) column-sum partials
#define WS_PART 0

// Fused pipeline kernel. Blocks [0, K1B) stream chunk k1c computing column-sum
// partials; blocks [K1B, K1B+K3B) consume chunk k3c (L3-warm: fetched by the
// PREVIOUS dispatch) doing MLP -> scores -> softmax -> out.
// Chunk args < 0 disable the corresponding role.
__global__ __launch_bounds__(256) void pipe(
    const float* __restrict__ ne,     // [B,N,H]
    const float* __restrict__ mask,   // [B,N]
    const float* __restrict__ times,  // [B]
    const float* __restrict__ W1,     // [H, 2H+1]
    const float* __restrict__ b1,     // [H]
    const float* __restrict__ Wq,     // [H,H]
    const float* __restrict__ Wk,     // [H,H]
    const int*   __restrict__ idxc,   // [B]
    float* __restrict__ ws,
    float* __restrict__ out,          // [B,N]
    int k1c, int k3c)
{
    __shared__ float smem[NN + 160];  // carved: scores / partials / MLP scratch
    const int tid = threadIdx.x;

    if ((int)blockIdx.x < K1B) {
        // ---------------- K1 role: column-sum partials ----------------
        if (k1c < 0) return;
        const int blk = blockIdx.x;
        const int b   = k1c * CHUNK + (blk >> 2);
        const int p   = blk & (PP - 1);
        const int q8  = tid & 7;     // float4 chunk within 32-float row
        const int r   = tid >> 3;    // row offset 0..31

        float* s_part = smem;        // 256*4 floats

        const float* base = ne + (size_t)b * (NN * HH)
                               + (size_t)(p * RK1 + r) * HH + q8 * 4;
        float a0 = 0.f, a1 = 0.f, a2 = 0.f, a3 = 0.f;
        #pragma unroll 8
        for (int i = 0; i < RK1 / 32; ++i) {           // 32 iters
            const float4 v = *reinterpret_cast<const float4*>(base + i * (32 * HH));
            a0 += v.x; a1 += v.y; a2 += v.z; a3 += v.w;
        }
        *reinterpret_cast<float4*>(&s_part[tid * 4]) = make_float4(a0, a1, a2, a3);
        __syncthreads();

        // deterministic fixed-order reduce
        if (tid < HH) {
            const int q = tid >> 2, j = tid & 3;
            float s = 0.f;
            #pragma unroll
            for (int rr = 0; rr < 32; ++rr) s += s_part[(rr * 8 + q) * 4 + j];
            ws[WS_PART + (b * PP + p) * HH + tid] = s;
        }
        return;
    }

    // ---------------- K3 role: MLP prelude + scores + softmax ----------------
    if (k3c < 0) return;
    const int b   = k3c * CHUNK + ((int)blockIdx.x - K1B);
    const int q8  = tid & 7;
    const int r   = tid >> 3;        // 0..31

    float* s_scores = smem;          // [NN)
    float* sh_avg   = smem + NN;         // [32)
    float* sh_f     = smem + NN + 32;    // [32)
    float* sh_emb   = smem + NN + 64;    // [32)
    float* sh_qk    = smem + NN + 96;    // [32)
    float* red_buf  = smem + NN + 128;   // [4)

    // prelude: rebuild avg from partials, gather f, tiny MLP -> qk
    if (tid < HH) {
        float s = 0.f;
        #pragma unroll
        for (int p = 0; p < PP; ++p) s += ws[WS_PART + (b * PP + p) * HH + tid];
        sh_avg[tid] = s * (1.0f / (float)NN);
        sh_f[tid]   = ne[(size_t)b * (NN * HH) + (size_t)idxc[b] * HH + tid];
    }
    __syncthreads();
    if (tid < HH) {
        const float t = times[b];
        const float* w = W1 + tid * (2 * HH + 1);
        float e = b1[tid];
        #pragma unroll
        for (int j = 0; j < HH; ++j) e += sh_avg[j] * w[j];
        #pragma unroll
        for (int j = 0; j < HH; ++j) e += sh_f[j] * w[HH + j];
        e += t * w[2 * HH];
        sh_emb[tid] = e;
    }
    __syncthreads();
    if (tid < HH) {  // q = emb @ Wq^T  (reuse sh_f)
        const float* w = Wq + tid * HH;
        float qv = 0.f;
        #pragma unroll
        for (int j = 0; j < HH; ++j) qv += sh_emb[j] * w[j];
        sh_f[tid] = qv;
    }
    __syncthreads();
    if (tid < HH) {  // qk[j] = sum_h q[h]*Wk[h,j], scaled 1/sqrt(H)
        float s = 0.f;
        #pragma unroll
        for (int h = 0; h < HH; ++h) s += sh_f[h] * Wk[h * HH + tid];
        sh_qk[tid] = s * 0.17677669529663687f;
    }
    __syncthreads();

    const float kq0 = sh_qk[q8 * 4 + 0];
    const float kq1 = sh_qk[q8 * 4 + 1];
    const float kq2 = sh_qk[q8 * 4 + 2];
    const float kq3 = sh_qk[q8 * 4 + 3];

    const float* base = ne + (size_t)b * (NN * HH) + (size_t)r * HH + q8 * 4;

    // raw dot products into LDS (reads should be L3-hits)
    #pragma unroll 8
    for (int i = 0; i < NN / 32; ++i) {                // 128 iters
        const float4 v = *reinterpret_cast<const float4*>(base + i * (32 * HH));
        float p = v.x * kq0 + v.y * kq1 + v.z * kq2 + v.w * kq3;
        p += __shfl_xor(p, 1);
        p += __shfl_xor(p, 2);
        p += __shfl_xor(p, 4);
        if (q8 == 0) s_scores[r + i * 32] = p;
    }
    __syncthreads();

    // apply mask (coalesced), block max
    const float* mrow = mask + (size_t)b * NN;
    float lmax = -INFINITY;
    #pragma unroll
    for (int k = 0; k < NN / 256; ++k) {
        const int n = tid + k * 256;
        const float sc = s_scores[n] - mrow[n] * 999999999.0f;
        s_scores[n] = sc;
        lmax = fmaxf(lmax, sc);
    }
    #pragma unroll
    for (int m = 1; m < 64; m <<= 1) lmax = fmaxf(lmax, __shfl_xor(lmax, m));
    if ((tid & 63) == 0) red_buf[tid >> 6] = lmax;
    __syncthreads();
    const float bmax = fmaxf(fmaxf(red_buf[0], red_buf[1]),
                             fmaxf(red_buf[2], red_buf[3]));

    // exp + sum
    float lsum = 0.f;
    #pragma unroll
    for (int k = 0; k < NN / 256; ++k) {
        const int n = tid + k * 256;
        const float e = expf(s_scores[n] - bmax);
        s_scores[n] = e;
        lsum += e;
    }
    #pragma unroll
    for (int m = 1; m < 64; m <<= 1) lsum += __shfl_xor(lsum, m);
    __syncthreads();                       // red_buf (max) reads done
    if ((tid & 63) == 0) red_buf[tid >> 6] = lsum;
    __syncthreads();
    const float inv = 1.0f / (red_buf[0] + red_buf[1] + red_buf[2] + red_buf[3]);

    float* orow = out + (size_t)b * NN;
    #pragma unroll
    for (int k = 0; k < NN / 256; ++k) {
        const int n = tid + k * 256;
        orow[n] = s_scores[n] * inv;
    }
}

extern "C" void kernel_launch(void* const* d_in, const int* in_sizes, int n_in,
                              void* d_out, int out_size, void* d_ws, size_t ws_size,
                              hipStream_t stream) {
    (void)in_sizes; (void)n_in; (void)ws_size; (void)out_size;
    const float* ne    = (const float*)d_in[0];
    const float* mask  = (const float*)d_in[1];
    const float* times = (const float*)d_in[2];
    // d_in[3] = vf, unused (idxc path taken)
    const float* W1    = (const float*)d_in[4];
    const float* b1    = (const float*)d_in[5];
    const float* Wq    = (const float*)d_in[6];
    const float* Wk    = (const float*)d_in[7];
    const int*   idxc  = (const int*)d_in[8];
    float* out = (float*)d_out;
    float* ws  = (float*)d_ws;

    // software pipeline: K1(c) produces chunk c's partials & L3 residency;
    // next dispatch runs K3(c) (L3-warm re-read) alongside K1(c+1).
    pipe<<<dim3(K1B), dim3(256), 0, stream>>>(
        ne, mask, times, W1, b1, Wq, Wk, idxc, ws, out, 0, -1);
    for (int c = 1; c < NCH; ++c) {
        pipe<<<dim3(K1B + K3B), dim3(256), 0, stream>>>(
            ne, mask, times, W1, b1, Wq, Wk, idxc, ws, out, c, c - 1);
    }
    pipe<<<dim3(K1B + K3B), dim3(256), 0, stream>>>(
        ne, mask, times, W1, b1, Wq, Wk, idxc, ws, out, -1, NCH - 1);
}

// Round 8
// 213.239 us; speedup vs baseline: 2.8945x; 2.8945x over previous
//
#include <hip/hip_runtime.h>
#include <math.h>

#define BB 1024
#define NN 4096
#define HH 32
#define PP 4                 // K1 partial blocks per batch
#define RK1 (NN / PP)        // 1024 rows per K1 block
#define QQ 4                 // K3 quarter-blocks per batch
#define RQ (NN / QQ)         // 1024 rows per K3a block

// ws layout (floats)
#define WS_PART 0                        // [BB*PP*HH) column-sum partials
#define WS_QK   (BB * PP * HH)           // [BB*HH) folded query vectors
#define WS_MS   (WS_QK + BB * HH)        // [BB*QQ*2) per-quarter (max, sum)

// ---------------- K1: per-batch column-sum partials (unchanged from R4) ----
__global__ __launch_bounds__(256) void k1_colsum(
    const float* __restrict__ ne, float* __restrict__ ws)
{
    const int blk = blockIdx.x;
    const int b   = blk >> 2;
    const int p   = blk & (PP - 1);
    const int tid = threadIdx.x;
    const int q8  = tid & 7;
    const int r   = tid >> 3;

    __shared__ float s_part[256 * 4];

    const float* base = ne + (size_t)b * (NN * HH)
                           + (size_t)(p * RK1 + r) * HH + q8 * 4;
    float a0 = 0.f, a1 = 0.f, a2 = 0.f, a3 = 0.f;
    #pragma unroll 8
    for (int i = 0; i < RK1 / 32; ++i) {
        const float4 v = *reinterpret_cast<const float4*>(base + i * (32 * HH));
        a0 += v.x; a1 += v.y; a2 += v.z; a3 += v.w;
    }
    *reinterpret_cast<float4*>(&s_part[tid * 4]) = make_float4(a0, a1, a2, a3);
    __syncthreads();

    if (tid < HH) {
        const int q = tid >> 2, j = tid & 3;
        float s = 0.f;
        #pragma unroll
        for (int rr = 0; rr < 32; ++rr) s += s_part[(rr * 8 + q) * 4 + j];
        ws[WS_PART + (b * PP + p) * HH + tid] = s;
    }
}

// ---------------- K2: per-batch tiny MLP -> qk (unchanged from R4) --------
__global__ __launch_bounds__(64) void k2_mlp(
    const float* __restrict__ ne, const float* __restrict__ times,
    const float* __restrict__ W1, const float* __restrict__ b1,
    const float* __restrict__ Wq, const float* __restrict__ Wk,
    const int* __restrict__ idxc, float* __restrict__ ws)
{
    const int b   = blockIdx.x;
    const int tid = threadIdx.x;
    __shared__ float sh_avg[HH], sh_f[HH], sh_emb[HH], sh_q[HH];

    if (tid < HH) {
        float s = 0.f;
        #pragma unroll
        for (int p = 0; p < PP; ++p) s += ws[WS_PART + (b * PP + p) * HH + tid];
        sh_avg[tid] = s * (1.0f / (float)NN);
        sh_f[tid]   = ne[(size_t)b * (NN * HH) + (size_t)idxc[b] * HH + tid];
    }
    __syncthreads();
    if (tid < HH) {
        const float t = times[b];
        const float* w = W1 + tid * (2 * HH + 1);
        float e = b1[tid];
        #pragma unroll
        for (int j = 0; j < HH; ++j) e += sh_avg[j] * w[j];
        #pragma unroll
        for (int j = 0; j < HH; ++j) e += sh_f[j] * w[HH + j];
        e += t * w[2 * HH];
        sh_emb[tid] = e;
    }
    __syncthreads();
    if (tid < HH) {
        const float* w = Wq + tid * HH;
        float qv = 0.f;
        #pragma unroll
        for (int j = 0; j < HH; ++j) qv += sh_emb[j] * w[j];
        sh_q[tid] = qv;
    }
    __syncthreads();
    if (tid < HH) {
        float s = 0.f;
        #pragma unroll
        for (int h = 0; h < HH; ++h) s += sh_q[h] * Wk[h * HH + tid];
        ws[WS_QK + b * HH + tid] = s * 0.17677669529663687f;   // 1/sqrt(32)
    }
}

// ---------------- K3a: quarter-row scores + local softmax ----------------
// grid = BB*QQ blocks x 256 thr, ~4.3 KB LDS -> 8 blocks/CU, 32 waves/CU.
// Writes e = exp(score - m_local) into out; (m_local, sum_local) into ws.
__global__ __launch_bounds__(256) void k3a_scores(
    const float* __restrict__ ne, const float* __restrict__ mask,
    const float* __restrict__ ws, float* __restrict__ out,
    float* __restrict__ ws_ms)
{
    const int blk = blockIdx.x;
    const int b   = blk >> 2;
    const int q   = blk & (QQ - 1);
    const int tid = threadIdx.x;
    const int q8  = tid & 7;
    const int r   = tid >> 3;    // 0..31

    __shared__ float s_scores[RQ];    // 4 KB
    __shared__ float sh_qk[HH];
    __shared__ float red_buf[4];
    __shared__ float red_sum[4];

    if (tid < HH) sh_qk[tid] = ws[WS_QK + b * HH + tid];

    // coalesced mask slice for this quarter (1 float4 per thread), loaded early
    const float4 mv = *reinterpret_cast<const float4*>(
        mask + (size_t)b * NN + q * RQ + tid * 4);
    __syncthreads();

    const float kq0 = sh_qk[q8 * 4 + 0];
    const float kq1 = sh_qk[q8 * 4 + 1];
    const float kq2 = sh_qk[q8 * 4 + 2];
    const float kq3 = sh_qk[q8 * 4 + 3];

    const float* base = ne + (size_t)b * (NN * HH)
                           + (size_t)(q * RQ + r) * HH + q8 * 4;

    #pragma unroll 8
    for (int i = 0; i < RQ / 32; ++i) {               // 32 iters
        const float4 v = *reinterpret_cast<const float4*>(base + i * (32 * HH));
        float p = v.x * kq0 + v.y * kq1 + v.z * kq2 + v.w * kq3;
        p += __shfl_xor(p, 1);
        p += __shfl_xor(p, 2);
        p += __shfl_xor(p, 4);
        if (q8 == 0) s_scores[r + i * 32] = p;
    }
    __syncthreads();

    // each thread owns 4 consecutive scores; apply mask, local max
    const float4 s4 = *reinterpret_cast<const float4*>(&s_scores[tid * 4]);
    float sc0 = s4.x - mv.x * 999999999.0f;
    float sc1 = s4.y - mv.y * 999999999.0f;
    float sc2 = s4.z - mv.z * 999999999.0f;
    float sc3 = s4.w - mv.w * 999999999.0f;

    float lmax = fmaxf(fmaxf(sc0, sc1), fmaxf(sc2, sc3));
    #pragma unroll
    for (int m = 1; m < 64; m <<= 1) lmax = fmaxf(lmax, __shfl_xor(lmax, m));
    if ((tid & 63) == 0) red_buf[tid >> 6] = lmax;
    __syncthreads();
    const float bmax = fmaxf(fmaxf(red_buf[0], red_buf[1]),
                             fmaxf(red_buf[2], red_buf[3]));

    const float e0 = expf(sc0 - bmax);
    const float e1 = expf(sc1 - bmax);
    const float e2 = expf(sc2 - bmax);
    const float e3 = expf(sc3 - bmax);
    float lsum = (e0 + e1) + (e2 + e3);
    #pragma unroll
    for (int m = 1; m < 64; m <<= 1) lsum += __shfl_xor(lsum, m);
    if ((tid & 63) == 0) red_sum[tid >> 6] = lsum;

    // coalesced e-value write
    *reinterpret_cast<float4*>(out + (size_t)b * NN + q * RQ + tid * 4) =
        make_float4(e0, e1, e2, e3);

    __syncthreads();
    if (tid == 0) {
        const float bsum = (red_sum[0] + red_sum[1]) + (red_sum[2] + red_sum[3]);
        ws_ms[(b * QQ + q) * 2 + 0] = bmax;
        ws_ms[(b * QQ + q) * 2 + 1] = bsum;
    }
}

// ---------------- K3b: combine quarters, rescale in place ----------------
// grid = BB*QQ blocks x 256 thr. Pure elementwise stream over out.
__global__ __launch_bounds__(256) void k3b_rescale(
    const float* __restrict__ ws_ms, float* __restrict__ out)
{
    const int blk = blockIdx.x;
    const int b   = blk >> 2;
    const int q   = blk & (QQ - 1);
    const int tid = threadIdx.x;

    const float m0 = ws_ms[(b * QQ + 0) * 2 + 0], s0 = ws_ms[(b * QQ + 0) * 2 + 1];
    const float m1 = ws_ms[(b * QQ + 1) * 2 + 0], s1 = ws_ms[(b * QQ + 1) * 2 + 1];
    const float m2 = ws_ms[(b * QQ + 2) * 2 + 0], s2 = ws_ms[(b * QQ + 2) * 2 + 1];
    const float m3 = ws_ms[(b * QQ + 3) * 2 + 0], s3 = ws_ms[(b * QQ + 3) * 2 + 1];

    const float M = fmaxf(fmaxf(m0, m1), fmaxf(m2, m3));
    const float S = s0 * expf(m0 - M) + s1 * expf(m1 - M)
                  + s2 * expf(m2 - M) + s3 * expf(m3 - M);
    const float mq = (q == 0) ? m0 : (q == 1) ? m1 : (q == 2) ? m2 : m3;
    const float scale = expf(mq - M) / S;

    float* p = out + (size_t)b * NN + q * RQ + tid * 4;
    const float4 v = *reinterpret_cast<const float4*>(p);
    *reinterpret_cast<float4*>(p) =
        make_float4(v.x * scale, v.y * scale, v.z * scale, v.w * scale);
}

extern "C" void kernel_launch(void* const* d_in, const int* in_sizes, int n_in,
                              void* d_out, int out_size, void* d_ws, size_t ws_size,
                              hipStream_t stream) {
    (void)in_sizes; (void)n_in; (void)ws_size; (void)out_size;
    const float* ne    = (const float*)d_in[0];
    const float* mask  = (const float*)d_in[1];
    const float* times = (const float*)d_in[2];
    // d_in[3] = vf, unused (idxc path taken)
    const float* W1    = (const float*)d_in[4];
    const float* b1    = (const float*)d_in[5];
    const float* Wq    = (const float*)d_in[6];
    const float* Wk    = (const float*)d_in[7];
    const int*   idxc  = (const int*)d_in[8];
    float* out = (float*)d_out;
    float* ws  = (float*)d_ws;

    k1_colsum<<<dim3(BB * PP), dim3(256), 0, stream>>>(ne, ws);
    k2_mlp<<<dim3(BB), dim3(64), 0, stream>>>(ne, times, W1, b1, Wq, Wk, idxc, ws);
    k3a_scores<<<dim3(BB * QQ), dim3(256), 0, stream>>>(ne, mask, ws, out, ws + WS_MS);
    k3b_rescale<<<dim3(BB * QQ), dim3(256), 0, stream>>>(ws + WS_MS, out);
}